// Round 7
// baseline (42.102 us; speedup 1.0000x reference)
//
#include <hip/hip_runtime.h>
#include <hip/hip_bf16.h>

#define DIN  1024
#define DOUT 1024
#define MROWS 8192   // B*S = 4*2048

#define BM 256
#define BN 128
#define BK 32
#define NKT (DIN / BK)   // 32 K-tiles

typedef __attribute__((ext_vector_type(8))) short short8;
typedef __attribute__((ext_vector_type(4))) float f32x4;

__device__ __forceinline__ ushort f2bf(float f) {
    union { float f; unsigned u; } x; x.f = f;
    unsigned u = x.u + 0x7fffu + ((x.u >> 16) & 1u);  // RNE
    return (ushort)(u >> 16);
}

// ---------- prep: Wv [K][N] f32 -> WvT [N][K] bf16 (tiled transpose, ~6MB) ----------
__global__ void prep_wt(const float* __restrict__ W, ushort* __restrict__ Wt) {
    __shared__ float tile[32][33];
    const int t  = blockIdx.x;
    const int bx = (t & 31) * 32;      // n base
    const int by = (t >> 5) * 32;      // k base
    const int tx = threadIdx.x & 31;
    const int ty = threadIdx.x >> 5;   // 0..7
#pragma unroll
    for (int i = 0; i < 32; i += 8)
        tile[ty + i][tx] = W[(size_t)(by + ty + i) * DOUT + (bx + tx)];
    __syncthreads();
#pragma unroll
    for (int i = 0; i < 32; i += 8)
        Wt[(size_t)(bx + ty + i) * DIN + (by + tx)] = f2bf(tile[tx][ty + i]);
}

// ---------- fused GEMM: C = cvt_bf16(X) @ WvT^T + bias ----------
// R2's proven DMA/phase structure, but A staged as RAW F32 straight from X
// via global_load_lds (no Xb prep pass!). bf16 conversion happens in-register
// after the LDS frag read (v_cvt_pk_bf16_f32, RNE). BK=32 so 3-deep buffers
// fit: 3 x (32K A-f32 + 8K B-bf16) = 120 KiB. 2-tiles-ahead prefetch,
// counted vmcnt(5), 2 barriers/phase, 16-MFMA clusters under setprio.
__global__ __launch_bounds__(512, 2) void gemm_fused(
    const float*  __restrict__ X,     // [8192][1024] f32
    const ushort* __restrict__ Wt,    // [1024 n][1024 k] bf16
    const float*  __restrict__ bias,  // [1024]
    float* __restrict__ out)          // [8192][1024] f32
{
    __shared__ float  As[3][BM * BK];   // 3 x 32 KiB (f32)
    __shared__ ushort Bs[3][BN * BK];   // 3 x  8 KiB (bf16)   total 120 KiB

    const int tid  = threadIdx.x;
    const int lane = tid & 63;
    const int wid  = tid >> 6;     // 0..7
    const int wr   = wid >> 1;     // 0..3  (wave M slab, 64 rows)
    const int wc   = wid & 1;      // 0..1  (wave N slab, 64 cols)
    const int g    = lane >> 4;    // k-group 0..3

    // XCD-aware bijective swizzle: 256 blocks = 8 XCDs x 32 (n fastest).
    const int bid = blockIdx.x;
    const int swz = (bid & 7) * 32 + (bid >> 3);
    const int bm = (swz >> 3) * BM;
    const int bn = (swz & 7) * BN;

    // Stage K-tile kt into buffer b: A = 4 gload_lds w16 (f32, 8 slots/row,
    // source slot ^= row&7), B = 1 gload_lds w16 (bf16, 4 slots/row, ^row&3).
    // LDS dest LINEAR (rule #21: swizzle on source + read, involution).
    auto stage = [&](int b, int kt) {
#pragma unroll
        for (int i = 0; i < 4; ++i) {
            const int c   = i * 512 + tid;      // 16B chunk 0..2047
            const int row = c >> 3;             // 0..255
            const int sc  = (c & 7) ^ (row & 7);
            __builtin_amdgcn_global_load_lds(
                (const __attribute__((address_space(1))) void*)(X + (size_t)(bm + row) * DIN + kt * BK + sc * 4),
                (__attribute__((address_space(3))) void*)(&As[b][(i * 512 + wid * 64) * 4]),
                16, 0, 0);
        }
        {
            const int c   = tid;                // 0..511
            const int row = c >> 2;             // 0..127
            const int sc  = (c & 3) ^ (row & 3);
            __builtin_amdgcn_global_load_lds(
                (const __attribute__((address_space(1))) void*)(Wt + (size_t)(bn + row) * DIN + kt * BK + sc * 8),
                (__attribute__((address_space(3))) void*)(&Bs[b][wid * 64 * 8]),
                16, 0, 0);
        }
    };

    f32x4 acc[4][4];
#pragma unroll
    for (int i = 0; i < 4; ++i)
#pragma unroll
        for (int j = 0; j < 4; ++j)
            acc[i][j] = (f32x4){0.f, 0.f, 0.f, 0.f};

    const int am  = wr * 64 + (lane & 15);
    const int bnr = wc * 64 + (lane & 15);

    // One phase = one K-tile: 8 A-b128 (f32) + 4 B-b128 reads, cvt_pk to bf16,
    // optional stage(t+2), barrier, lgkm(0), 16 MFMA, counted vmcnt, barrier.
    auto phase = [&](int buf, bool doStage, int skt, int wait, bool endBar) {
        short8 af[4], bfr[4];
#pragma unroll
        for (int i = 0; i < 4; ++i) {
            const int row = am + i * 16;
            const int s0 = (2 * g)     ^ (row & 7);
            const int s1 = (2 * g + 1) ^ (row & 7);
            const f32x4 a0 = *(const f32x4*)(&As[buf][row * BK + s0 * 4]);
            const f32x4 a1 = *(const f32x4*)(&As[buf][row * BK + s1 * 4]);
            union { unsigned u[4]; short8 v; } p;
            asm("v_cvt_pk_bf16_f32 %0, %1, %2" : "=v"(p.u[0]) : "v"(a0[0]), "v"(a0[1]));
            asm("v_cvt_pk_bf16_f32 %0, %1, %2" : "=v"(p.u[1]) : "v"(a0[2]), "v"(a0[3]));
            asm("v_cvt_pk_bf16_f32 %0, %1, %2" : "=v"(p.u[2]) : "v"(a1[0]), "v"(a1[1]));
            asm("v_cvt_pk_bf16_f32 %0, %1, %2" : "=v"(p.u[3]) : "v"(a1[2]), "v"(a1[3]));
            af[i] = p.v;
        }
#pragma unroll
        for (int j = 0; j < 4; ++j) {
            const int row = bnr + j * 16;
            const int s = g ^ (row & 3);
            bfr[j] = *(const short8*)(&Bs[buf][row * BK + s * 8]);
        }
        if (doStage) stage((skt) % 3, skt);
        __builtin_amdgcn_s_barrier();
        asm volatile("s_waitcnt lgkmcnt(0)" ::: "memory");
        __builtin_amdgcn_sched_barrier(0);
        __builtin_amdgcn_s_setprio(1);
#pragma unroll
        for (int i = 0; i < 4; ++i)
#pragma unroll
            for (int j = 0; j < 4; ++j)
                acc[i][j] = __builtin_amdgcn_mfma_f32_16x16x32_bf16(af[i], bfr[j], acc[i][j], 0, 0, 0);
        __builtin_amdgcn_s_setprio(0);
        if (wait == 5)      asm volatile("s_waitcnt vmcnt(5)" ::: "memory");
        else if (wait == 0) asm volatile("s_waitcnt vmcnt(0)" ::: "memory");
        if (endBar) __builtin_amdgcn_s_barrier();
    };

    // ---- prologue: stage tiles 0,1 (10 loads); tile 0 landed after vmcnt(5) ----
    stage(0, 0);
    stage(1, 1);
    asm volatile("s_waitcnt vmcnt(5)" ::: "memory");
    __builtin_amdgcn_sched_barrier(0);
    __builtin_amdgcn_s_barrier();

    // ---- main loop: compute tile t, stage tile t+2 into buffer (t+2)%3 ----
    for (int t = 0; t < NKT - 2; ++t)                  // t = 0..29
        phase(t % 3, true, t + 2, 5, true);
    phase((NKT - 2) % 3, false, 0, 0, true);           // t=30: drain tile-31 loads
    phase((NKT - 1) % 3, false, 0, -1, false);         // t=31: tail

    // ---- epilogue: bias + store. C/D: col = lane&15, row = (lane>>4)*4 + r ----
    const int crow = bm + wr * 64 + (lane >> 4) * 4;
    const int ccol = bn + wc * 64 + (lane & 15);
#pragma unroll
    for (int j = 0; j < 4; ++j) {
        const int col = ccol + j * 16;
        const float bval = bias[col];
#pragma unroll
        for (int i = 0; i < 4; ++i) {
#pragma unroll
            for (int r = 0; r < 4; ++r)
                out[(size_t)(crow + i * 16 + r) * DOUT + col] = acc[i][j][r] + bval;
        }
    }
}

// ---------- fallback (only if workspace too small): naive f32 ----------
__global__ void gemm_naive(const float* __restrict__ X, const float* __restrict__ W,
                           const float* __restrict__ b, float* __restrict__ out) {
    int n = blockIdx.x * blockDim.x + threadIdx.x;
    int m = blockIdx.y;
    float acc = b[n];
    for (int k = 0; k < DIN; ++k)
        acc += X[(size_t)m * DIN + k] * W[(size_t)k * DOUT + n];
    out[(size_t)m * DOUT + n] = acc;
}

extern "C" void kernel_launch(void* const* d_in, const int* in_sizes, int n_in,
                              void* d_out, int out_size, void* d_ws, size_t ws_size,
                              hipStream_t stream) {
    // setup_inputs order: X, Wq, bq, Wk, bk, Wv, bv
    const float* X  = (const float*)d_in[0];
    const float* Wv = (const float*)d_in[5];
    const float* bv = (const float*)d_in[6];
    float* out = (float*)d_out;

    const size_t wt_elems = (size_t)DOUT * DIN;
    if (ws_size < wt_elems * sizeof(ushort)) {
        dim3 g(DOUT / 256, MROWS);
        gemm_naive<<<g, 256, 0, stream>>>(X, Wv, bv, out);
        return;
    }

    ushort* Wt = (ushort*)d_ws;
    prep_wt<<<1024, 256, 0, stream>>>(Wv, Wt);
    gemm_fused<<<256, 512, 0, stream>>>(X, Wt, bv, out);
}